// Round 1
// baseline (2092.734 us; speedup 1.0000x reference)
//
#include <hip/hip_runtime.h>

// Seq2Seq GRU (encoder 256 steps + AR decoder 128 steps), fp32.
// B=8192, H=64, NF=NO=8.
// Strategy: batch elements are independent -> persistent blocks, each owns 16
// batch elements for all 384 steps. Weights in registers (3 gate rows x K/2
// per thread), h state in LDS (ping-pong), broadcast reads, shfl_xor K-reduce.

#define SEQ_LEN   256
#define LABEL_LEN 128
#define BATCH     8192
#define NF        8
#define NO        8
#define H         64

#define BB 16          // batch per block
#define HP 68          // padded h row stride in floats (68: 16B aligned, bank-spread)
#define NBLOCKS (BATCH / BB)   // 512

__device__ __forceinline__ float sigmoid_f(float x) {
    float t = __expf(-x);
    return __fdividef(1.0f, 1.0f + t);
}

__device__ __forceinline__ float tanh_f(float x) {
    // tanh(x) = sign(x) * (1 - e^{-2|x|}) / (1 + e^{-2|x|})  -- NaN-safe
    float ax = fabsf(x);
    float t = __expf(-2.0f * ax);
    float y = __fdividef(1.0f - t, 1.0f + t);
    return copysignf(y, x);
}

// One GRU step for 8 batch elements (this wave-pair's group).
// Each thread: hidden index j, K-half kh. Weights for rows (j, H+j, 2H+j),
// k in [32*kh, 32*kh+32) are in registers.
__device__ __forceinline__ void gru_cell(
    const float4 inp[8],              // x[b][4*kh .. 4*kh+4) per m
    const float* __restrict__ hc,     // LDS current h, [BB][HP]
    float*       __restrict__ hn_,    // LDS next h
    const float (&wr)[32], const float (&wz)[32], const float (&wn)[32],
    const float (&wxr)[4], const float (&wxz)[4], const float (&wxn)[4],
    float br, float bz, float bin, float bhn,
    int g, int j, int kh, int kbase)
{
    #pragma unroll
    for (int m = 0; m < 8; ++m) {
        const int bl = 8 * g + m;
        const float* hrow = hc + bl * HP + kbase;
        float aR = 0.0f, aZ = 0.0f, aNh = 0.0f, aNi = 0.0f;
        #pragma unroll
        for (int c = 0; c < 8; ++c) {
            const float4 hv = *reinterpret_cast<const float4*>(hrow + 4 * c);
            aR  = fmaf(hv.x, wr[4*c+0], aR);
            aR  = fmaf(hv.y, wr[4*c+1], aR);
            aR  = fmaf(hv.z, wr[4*c+2], aR);
            aR  = fmaf(hv.w, wr[4*c+3], aR);
            aZ  = fmaf(hv.x, wz[4*c+0], aZ);
            aZ  = fmaf(hv.y, wz[4*c+1], aZ);
            aZ  = fmaf(hv.z, wz[4*c+2], aZ);
            aZ  = fmaf(hv.w, wz[4*c+3], aZ);
            aNh = fmaf(hv.x, wn[4*c+0], aNh);
            aNh = fmaf(hv.y, wn[4*c+1], aNh);
            aNh = fmaf(hv.z, wn[4*c+2], aNh);
            aNh = fmaf(hv.w, wn[4*c+3], aNh);
        }
        const float4 xi = inp[m];
        aR  = fmaf(xi.x, wxr[0], aR);
        aR  = fmaf(xi.y, wxr[1], aR);
        aR  = fmaf(xi.z, wxr[2], aR);
        aR  = fmaf(xi.w, wxr[3], aR);
        aZ  = fmaf(xi.x, wxz[0], aZ);
        aZ  = fmaf(xi.y, wxz[1], aZ);
        aZ  = fmaf(xi.z, wxz[2], aZ);
        aZ  = fmaf(xi.w, wxz[3], aZ);
        aNi = fmaf(xi.x, wxn[0], aNi);
        aNi = fmaf(xi.y, wxn[1], aNi);
        aNi = fmaf(xi.z, wxn[2], aNi);
        aNi = fmaf(xi.w, wxn[3], aNi);

        // combine the two K-halves (lane ^ 32)
        aR  += __shfl_xor(aR,  32);
        aZ  += __shfl_xor(aZ,  32);
        aNh += __shfl_xor(aNh, 32);
        aNi += __shfl_xor(aNi, 32);

        const float r  = sigmoid_f(aR + br);
        const float z  = sigmoid_f(aZ + bz);
        const float nn = tanh_f(aNi + bin + r * (aNh + bhn));
        const float hold = hc[bl * HP + j];
        const float hv_  = (1.0f - z) * nn + z * hold;
        if (kh == 0) hn_[bl * HP + j] = hv_;
    }
}

#define LOAD_WEIGHTS(Wih_, Whh_, bih_, bhh_) do {                              \
    _Pragma("unroll")                                                          \
    for (int k = 0; k < 32; ++k) {                                             \
        wr[k] = Whh_[(        j) * H + kbase + k];                             \
        wz[k] = Whh_[( H   +  j) * H + kbase + k];                             \
        wn[k] = Whh_[( 2*H +  j) * H + kbase + k];                             \
    }                                                                          \
    _Pragma("unroll")                                                          \
    for (int i = 0; i < 4; ++i) {                                              \
        wxr[i] = Wih_[(        j) * NF + 4 * kh + i];                          \
        wxz[i] = Wih_[( H   +  j) * NF + 4 * kh + i];                          \
        wxn[i] = Wih_[( 2*H +  j) * NF + 4 * kh + i];                          \
    }                                                                          \
    br  = bih_[j]       + bhh_[j];                                             \
    bz  = bih_[H + j]   + bhh_[H + j];                                         \
    bin = bih_[2*H + j];                                                       \
    bhn = bhh_[2*H + j];                                                       \
} while (0)

__global__ __launch_bounds__(256, 2) void seq2seq_gru_kernel(
    const float* __restrict__ x,    const float* __restrict__ xy,
    const float* __restrict__ eWih, const float* __restrict__ eWhh,
    const float* __restrict__ ebih, const float* __restrict__ ebhh,
    const float* __restrict__ dWih, const float* __restrict__ dWhh,
    const float* __restrict__ dbih, const float* __restrict__ dbhh,
    const float* __restrict__ Wout, const float* __restrict__ bout,
    float* __restrict__ out)
{
    __shared__ __align__(16) float hbufA[BB * HP];
    __shared__ __align__(16) float hbufB[BB * HP];
    __shared__ __align__(16) float out_lds[BB * NO];
    __shared__ __align__(16) float wout_lds[NO * HP];

    const int tid   = threadIdx.x;
    const int lane  = tid & 63;
    const int wv    = tid >> 6;     // 0..3
    const int jj    = lane & 31;
    const int kh    = lane >> 5;    // K-half 0/1
    const int jh    = wv & 1;       // hidden-half 0/1
    const int g     = wv >> 1;      // batch-group 0/1 (8 elems each)
    const int j     = 32 * jh + jj; // hidden index 0..63
    const int kbase = 32 * kh;
    const int b0    = (int)blockIdx.x * BB;

    // zero initial hidden state (buffer A)
    for (int i = tid; i < BB * HP; i += 256) hbufA[i] = 0.0f;
    // stage Wout for the decoder
    for (int i = tid; i < NO * H; i += 256) {
        const int o = i >> 6, k = i & 63;
        wout_lds[o * HP + k] = Wout[i];
    }
    const float bo = bout[lane & 7];

    float wr[32], wz[32], wn[32], wxr[4], wxz[4], wxn[4];
    float br, bz, bin, bhn;
    LOAD_WEIGHTS(eWih, eWhh, ebih, ebhh);

    __syncthreads();

    float* hc  = hbufA;
    float* hn_ = hbufB;

    // ---------------- encoder: 256 steps ----------------
    for (int t = 0; t < SEQ_LEN; ++t) {
        float4 inp[8];
        const float* xrow = x + ((size_t)t * BATCH + (b0 + 8 * g)) * NF + 4 * kh;
        #pragma unroll
        for (int m = 0; m < 8; ++m)
            inp[m] = *reinterpret_cast<const float4*>(xrow + m * NF);
        gru_cell(inp, hc, hn_, wr, wz, wn, wxr, wxz, wxn, br, bz, bin, bhn,
                 g, j, kh, kbase);
        __syncthreads();
        float* tmp = hc; hc = hn_; hn_ = tmp;
    }

    // ---------------- decoder: 128 steps ----------------
    LOAD_WEIGHTS(dWih, dWhh, dbih, dbhh);

    for (int d = 0; d < LABEL_LEN; ++d) {
        float4 inp[8];
        if (d == 0) {
            const float* xyrow = xy + (size_t)(b0 + 8 * g) * NO + 4 * kh;
            #pragma unroll
            for (int m = 0; m < 8; ++m)
                inp[m] = *reinterpret_cast<const float4*>(xyrow + m * NO);
        } else {
            #pragma unroll
            for (int m = 0; m < 8; ++m)
                inp[m] = *reinterpret_cast<const float4*>(
                    &out_lds[(8 * g + m) * NO + 4 * kh]);
        }
        gru_cell(inp, hc, hn_, wr, wz, wn, wxr, wxz, wxn, br, bz, bin, bhn,
                 g, j, kh, kbase);
        __syncthreads();   // h_new visible

        // out = h_new @ Wout^T + bout ; lane = (local batch 0..7) x (output 0..7)
        {
            const int ob = lane >> 3;
            const int oo = lane & 7;
            const float* hrow = hn_ + (8 * g + ob) * HP;
            const float* wrow = wout_lds + oo * HP;
            float acc = bo;
            #pragma unroll
            for (int c = 0; c < 16; ++c) {
                const float4 hv = *reinterpret_cast<const float4*>(hrow + 4 * c);
                const float4 wv4 = *reinterpret_cast<const float4*>(wrow + 4 * c);
                acc = fmaf(hv.x, wv4.x, acc);
                acc = fmaf(hv.y, wv4.y, acc);
                acc = fmaf(hv.z, wv4.z, acc);
                acc = fmaf(hv.w, wv4.w, acc);
            }
            if (jh == 0) {
                out_lds[(8 * g + ob) * NO + oo] = acc;
                out[(size_t)d * (BATCH * NO) + (size_t)(b0 + 8 * g + ob) * NO + oo] = acc;
            }
        }
        __syncthreads();   // out_lds visible for next step's input
        float* tmp = hc; hc = hn_; hn_ = tmp;
    }
}

extern "C" void kernel_launch(void* const* d_in, const int* in_sizes, int n_in,
                              void* d_out, int out_size, void* d_ws, size_t ws_size,
                              hipStream_t stream) {
    const float* x    = (const float*)d_in[0];
    const float* xy   = (const float*)d_in[1];
    const float* eWih = (const float*)d_in[2];
    const float* eWhh = (const float*)d_in[3];
    const float* ebih = (const float*)d_in[4];
    const float* ebhh = (const float*)d_in[5];
    const float* dWih = (const float*)d_in[6];
    const float* dWhh = (const float*)d_in[7];
    const float* dbih = (const float*)d_in[8];
    const float* dbhh = (const float*)d_in[9];
    const float* Wout = (const float*)d_in[10];
    const float* bout = (const float*)d_in[11];
    float* out = (float*)d_out;

    seq2seq_gru_kernel<<<NBLOCKS, 256, 0, stream>>>(
        x, xy, eWih, eWhh, ebih, ebhh, dWih, dWhh, dbih, dbhh, Wout, bout, out);
}